// Round 3
// baseline (1569.105 us; speedup 1.0000x reference)
//
#include <hip/hip_runtime.h>

#define NVN 20000
#define NCN 20000
#define NE  500000
#define HID 64
#define NLAYER 3

// transposed-weight table offsets (in floats)
#define T_V2C_W1 0          // [NL][128][64]  w1t[o][k]
#define T_V2C_W2 24576      // [NL][64][128]  w2t[o][k]
#define T_C2V_W1 49152
#define T_C2V_W2 73728
#define T_PV_W1  98304      // [64][64]
#define T_PC_W1  102400
#define T_PEV_W2 106496     // [32][64]
#define T_PEC_W2 108544
#define T_TOTAL  110592

__device__ __forceinline__ float relu_(float x) { return fmaxf(x, 0.0f); }

// ---------------- weight transpose (once per launch) ----------------
__global__ __launch_bounds__(256) void prep_kernel(
    const float* __restrict__ v2c_w1, const float* __restrict__ v2c_w2,
    const float* __restrict__ c2v_w1, const float* __restrict__ c2v_w2,
    const float* __restrict__ pv_w1, const float* __restrict__ pc_w1,
    const float* __restrict__ pev_w2, const float* __restrict__ pec_w2,
    float* __restrict__ t)
{
    int i = blockIdx.x * 256 + threadIdx.x;
    if (i >= T_TOTAL) return;
    float v;
    if (i < T_V2C_W2) {
        int j = i; int L = j >> 13, r = j & 8191, o = r >> 6, k = r & 63;
        v = v2c_w1[L * 8192 + k * 128 + o];
    } else if (i < T_C2V_W1) {
        int j = i - T_V2C_W2; int L = j >> 13, r = j & 8191, o = r >> 7, k = r & 127;
        v = v2c_w2[L * 8192 + k * 64 + o];
    } else if (i < T_C2V_W2) {
        int j = i - T_C2V_W1; int L = j >> 13, r = j & 8191, o = r >> 6, k = r & 63;
        v = c2v_w1[L * 8192 + k * 128 + o];
    } else if (i < T_PV_W1) {
        int j = i - T_C2V_W2; int L = j >> 13, r = j & 8191, o = r >> 7, k = r & 127;
        v = c2v_w2[L * 8192 + k * 64 + o];
    } else if (i < T_PC_W1) {
        int j = i - T_PV_W1; int o = j >> 6, k = j & 63;
        v = pv_w1[k * 64 + o];
    } else if (i < T_PEV_W2) {
        int j = i - T_PC_W1; int o = j >> 6, k = j & 63;
        v = pc_w1[k * 64 + o];
    } else if (i < T_PEC_W2) {
        int j = i - T_PEV_W2; int o = j >> 6, k = j & 63;
        v = pev_w2[k * 32 + o];
    } else {
        int j = i - T_PEC_W2; int o = j >> 6, k = j & 63;
        v = pec_w2[k * 32 + o];
    }
    t[i] = v;
}

// ---------------- CSR build ----------------
__global__ __launch_bounds__(256) void hist2_kernel(
    const int* __restrict__ dstA, const int* __restrict__ dstB,
    int* __restrict__ degA, int* __restrict__ degB)
{
    int e = blockIdx.x * 256 + threadIdx.x;
    if (e < NE) {
        atomicAdd(&degA[dstA[e]], 1);
        atomicAdd(&degB[dstB[e]], 1);
    }
}

// 2 blocks of 1024 threads; block 0 -> A, block 1 -> B (NVN == NCN)
__global__ __launch_bounds__(1024) void scan2_kernel(
    const int* __restrict__ degA, int* __restrict__ rowptrA, int* __restrict__ cursorA,
    const int* __restrict__ degB, int* __restrict__ rowptrB, int* __restrict__ cursorB)
{
    const int n = NCN;
    const int* deg = blockIdx.x ? degB : degA;
    int* rowptr    = blockIdx.x ? rowptrB : rowptrA;
    int* cursor    = blockIdx.x ? cursorB : cursorA;
    __shared__ int part[1024];
    int t = threadIdx.x;
    int chunk = (n + 1023) / 1024;
    int base = t * chunk;
    int sum = 0;
    for (int i = 0; i < chunk; ++i) {
        int idx = base + i;
        if (idx < n) sum += deg[idx];
    }
    part[t] = sum;
    __syncthreads();
    for (int off = 1; off < 1024; off <<= 1) {
        int v = (t >= off) ? part[t - off] : 0;
        __syncthreads();
        part[t] += v;
        __syncthreads();
    }
    int run = (t == 0) ? 0 : part[t - 1];
    for (int i = 0; i < chunk; ++i) {
        int idx = base + i;
        if (idx < n) {
            int d = deg[idx];
            rowptr[idx] = run;
            cursor[idx] = run;
            run += d;
        }
    }
    if (t == 1023) rowptr[n] = part[1023];
}

__global__ __launch_bounds__(256) void scatter2_kernel(
    const int* __restrict__ eiA, const float* __restrict__ ewA,
    int* __restrict__ curA, int2* __restrict__ pairA,
    const int* __restrict__ eiB, const float* __restrict__ ewB,
    int* __restrict__ curB, int2* __restrict__ pairB)
{
    int e = blockIdx.x * 256 + threadIdx.x;
    if (e >= NE) return;
    {
        int d = eiA[NE + e];
        int pos = atomicAdd(&curA[d], 1);
        pairA[pos] = make_int2(eiA[e], __float_as_int(ewA[e]));
    }
    {
        int d = eiB[NE + e];
        int pos = atomicAdd(&curB[d], 1);
        pairB[pos] = make_int2(eiB[e], __float_as_int(ewB[e]));
    }
}

// ---------------- Encoders (both node sets in one dispatch) ----------------
__global__ __launch_bounds__(256) void encode2_kernel(
    const float* __restrict__ xv, const float* __restrict__ pev,
    const float* __restrict__ ewv, const float* __restrict__ ebv,
    const float* __restrict__ pw1v, const float* __restrict__ pb1v,
    const float* __restrict__ pw2tv, const float* __restrict__ pb2v,
    const float* __restrict__ xc, const float* __restrict__ pec,
    const float* __restrict__ ewc, const float* __restrict__ ebc,
    const float* __restrict__ pw1c, const float* __restrict__ pb1c,
    const float* __restrict__ pw2tc, const float* __restrict__ pb2c,
    float* __restrict__ outv, float* __restrict__ outc)
{
    __shared__ float sh[4][64];
    const int VB = (NVN + 3) / 4;
    int wave = threadIdx.x >> 6, lane = threadIdx.x & 63;
    int b = blockIdx.x;
    bool isC = (b >= VB);
    const float* x    = isC ? xc : xv;
    const float* pe   = isC ? pec : pev;
    const float* ew   = isC ? ewc : ewv;
    const float* eb   = isC ? ebc : ebv;
    const float* pw1  = isC ? pw1c : pw1v;
    const float* pb1  = isC ? pb1c : pb1v;
    const float* pw2t = isC ? pw2tc : pw2tv;
    const float* pb2  = isC ? pb2c : pb2v;
    float* out = isC ? outc : outv;
    int N = isC ? NCN : NVN;
    int n = (isC ? b - VB : b) * 4 + wave;
    if (n >= N) return;

    float accp = pb1[lane], accm = accp;
#pragma unroll
    for (int k = 0; k < 8; ++k) {
        float p = pe[n * 8 + k];
        float w = pw1[k * 64 + lane];
        accp += p * w;
        accm -= p * w;
    }
    float hs = 0.5f * (relu_(accp) + relu_(accm));
    float* my = sh[wave];
    my[lane] = hs;
    __builtin_amdgcn_wave_barrier();
    int col = lane & 31;
    float peo = pb2[col];
    const float* wr = pw2t + col * 64;
#pragma unroll 4
    for (int k = 0; k < 64; k += 4) {
        float4 hv = *(const float4*)(my + k);
        float4 w4 = *(const float4*)(wr + k);
        peo += hv.x * w4.x + hv.y * w4.y + hv.z * w4.z + hv.w * w4.w;
    }
    float lino = x[n * 2 + 0] * ew[col] + x[n * 2 + 1] * ew[32 + col] + eb[col];
    float h = (lane < 32) ? lino : peo;
    out[n * 64 + lane] = relu_(h);
}

// ---------------- Fused GENConv + node MLP + pred head ----------------
// wave per dst node; lane = feature channel; xdst updated IN PLACE
__global__ __launch_bounds__(256) void conv_kernel(
    const float* __restrict__ xsrc,   // [Nsrc,64]
    float* __restrict__ xdst,         // [Ndst,64] read [n], write [n]
    const int* __restrict__ rowptr,   // [Ndst+1]
    const int2* __restrict__ pair,    // [E] (src, bitcast(weight)), dst-sorted
    const float* __restrict__ lew,    // [64]
    const float* __restrict__ leb,    // [64]
    const float* __restrict__ w1t,    // [128][64]
    const float* __restrict__ b1,     // [128]
    const float* __restrict__ w2t,    // [64][128]
    const float* __restrict__ b2,     // [64]
    const float* __restrict__ pw1t,   // [64][64]
    const float* __restrict__ pb1,    // [64]
    const float* __restrict__ pw2,    // [64]
    const float* __restrict__ pb2,    // [1]
    float* __restrict__ outp,         // write outp[n*NLAYER+layer]
    int N, int layer)
{
    __shared__ float sh[4][128];
    int wave = threadIdx.x >> 6, lane = threadIdx.x & 63;
    int n = blockIdx.x * 4 + wave;
    if (n >= N) return;

    int start = rowptr[n], end = rowptr[n + 1];
    float lw = lew[lane], lb = leb[lane];

    // chunked online softmax: 8 edges per chunk, gathers pipelined
    float m = -1e30f, den = 0.0f, num = 0.0f;
    for (int j = start; j < end; j += 8) {
        int idx[8]; float wv[8], msg[8];
#pragma unroll
        for (int c = 0; c < 8; ++c) {
            int jc = j + c; jc = (jc < end) ? jc : (end - 1);
            int2 p = pair[jc];
            idx[c] = p.x;
            wv[c] = __int_as_float(p.y);
        }
#pragma unroll
        for (int c = 0; c < 8; ++c) {
            float xv = xsrc[idx[c] * 64 + lane];
            float t = relu_(fmaf(wv[c], lw, xv + lb)) + 1e-7f;
            msg[c] = (j + c < end) ? t : -1e30f;
        }
        float a0 = fmaxf(msg[0], msg[1]), a1 = fmaxf(msg[2], msg[3]);
        float a2 = fmaxf(msg[4], msg[5]), a3 = fmaxf(msg[6], msg[7]);
        float cm = fmaxf(fmaxf(a0, a1), fmaxf(a2, a3));
        float mnew = fmaxf(m, cm);
        float sc = __expf(m - mnew);   // 0 on first chunk, 1 if max unchanged
        float cden = 0.0f, cnum = 0.0f;
#pragma unroll
        for (int c = 0; c < 8; ++c) {
            float e = __expf(msg[c] - mnew);  // 0 for padded slots
            cden += e;
            cnum = fmaf(e, msg[c], cnum);
        }
        den = fmaf(den, sc, cden);
        num = fmaf(num, sc, cnum);
        m = mnew;
    }
    float o = num / (den + 1e-16f) + xdst[n * 64 + lane];

    float* my = sh[wave];
    my[lane] = o;
    __builtin_amdgcn_wave_barrier();

    // 64 -> 128 (lane owns outputs 2l, 2l+1), weights transposed, float4
    float2 bb = ((const float2*)b1)[lane];
    float h0 = bb.x, h1 = bb.y;
    const float* wa = w1t + (2 * lane) * 64;
    const float* wb = w1t + (2 * lane + 1) * 64;
#pragma unroll 4
    for (int k = 0; k < 64; k += 4) {
        float4 ov = *(const float4*)(my + k);
        float4 a4 = *(const float4*)(wa + k);
        float4 b4 = *(const float4*)(wb + k);
        h0 += ov.x * a4.x + ov.y * a4.y + ov.z * a4.z + ov.w * a4.w;
        h1 += ov.x * b4.x + ov.y * b4.y + ov.z * b4.z + ov.w * b4.w;
    }
    h0 = relu_(h0);
    h1 = relu_(h1);
    __builtin_amdgcn_wave_barrier();
    ((float2*)my)[lane] = make_float2(h0, h1);  // h[2l], h[2l+1]
    __builtin_amdgcn_wave_barrier();

    // 128 -> 64 (lane owns output lane)
    float r = b2[lane];
    const float* w2r = w2t + lane * 128;
#pragma unroll 4
    for (int k = 0; k < 128; k += 4) {
        float4 hv = *(const float4*)(my + k);
        float4 w4 = *(const float4*)(w2r + k);
        r += hv.x * w4.x + hv.y * w4.y + hv.z * w4.z + hv.w * w4.w;
    }
    xdst[n * 64 + lane] = r;
    __builtin_amdgcn_wave_barrier();

    // pred head: relu(r@pw1+pb1)@pw2 + pb2
    my[lane] = r;
    __builtin_amdgcn_wave_barrier();
    float ph = pb1[lane];
    const float* pwr = pw1t + lane * 64;
#pragma unroll 4
    for (int k = 0; k < 64; k += 4) {
        float4 rv = *(const float4*)(my + k);
        float4 w4 = *(const float4*)(pwr + k);
        ph += rv.x * w4.x + rv.y * w4.y + rv.z * w4.z + rv.w * w4.w;
    }
    ph = relu_(ph);
    float partial = ph * pw2[lane];
#pragma unroll
    for (int off = 32; off > 0; off >>= 1)
        partial += __shfl_down(partial, off, 64);
    if (lane == 0) outp[n * NLAYER + layer] = partial + pb2[0];
}

extern "C" void kernel_launch(void* const* d_in, const int* in_sizes, int n_in,
                              void* d_out, int out_size, void* d_ws, size_t ws_size,
                              hipStream_t stream)
{
    const float* x_vals   = (const float*)d_in[0];
    const float* x_cons   = (const float*)d_in[1];
    const float* pe_vals  = (const float*)d_in[2];
    const float* pe_cons  = (const float*)d_in[3];
    const int*   ei_v2c   = (const int*)d_in[4];   // [2,E]
    const int*   ei_c2v   = (const int*)d_in[5];   // [2,E]
    const float* ew_v2c   = (const float*)d_in[6]; // [E,1]
    const float* ew_c2v   = (const float*)d_in[7];
    const float* enc_vals_w = (const float*)d_in[8];
    const float* enc_vals_b = (const float*)d_in[9];
    const float* pe_vals_w1 = (const float*)d_in[10];
    const float* pe_vals_b1 = (const float*)d_in[11];
    const float* pe_vals_w2 = (const float*)d_in[12];
    const float* pe_vals_b2 = (const float*)d_in[13];
    const float* enc_cons_w = (const float*)d_in[14];
    const float* enc_cons_b = (const float*)d_in[15];
    const float* pe_cons_w1 = (const float*)d_in[16];
    const float* pe_cons_b1 = (const float*)d_in[17];
    const float* pe_cons_w2 = (const float*)d_in[18];
    const float* pe_cons_b2 = (const float*)d_in[19];
    const float* v2c_edge_w = (const float*)d_in[20]; // [NL,1,64]
    const float* v2c_edge_b = (const float*)d_in[21]; // [NL,64]
    const float* v2c_w1     = (const float*)d_in[22]; // [NL,64,128]
    const float* v2c_b1     = (const float*)d_in[23]; // [NL,128]
    const float* v2c_w2     = (const float*)d_in[24]; // [NL,128,64]
    const float* v2c_b2     = (const float*)d_in[25]; // [NL,64]
    const float* c2v_edge_w = (const float*)d_in[26];
    const float* c2v_edge_b = (const float*)d_in[27];
    const float* c2v_w1     = (const float*)d_in[28];
    const float* c2v_b1     = (const float*)d_in[29];
    const float* c2v_w2     = (const float*)d_in[30];
    const float* c2v_b2     = (const float*)d_in[31];
    const float* pred_vals_w1 = (const float*)d_in[32];
    const float* pred_vals_b1 = (const float*)d_in[33];
    const float* pred_vals_w2 = (const float*)d_in[34];
    const float* pred_vals_b2 = (const float*)d_in[35];
    const float* pred_cons_w1 = (const float*)d_in[36];
    const float* pred_cons_b1 = (const float*)d_in[37];
    const float* pred_cons_w2 = (const float*)d_in[38];
    const float* pred_cons_b2 = (const float*)d_in[39];

    float* out = (float*)d_out;
    float* out_c = out + (size_t)NVN * NLAYER;

    const size_t NF = (size_t)NVN * 64;

    // Workspace layout
    float* ws     = (float*)d_ws;
    float* feat_v = ws;                 // NF (in-place across layers)
    float* feat_c = feat_v + NF;        // NF
    float* twt    = feat_c + NF;        // T_TOTAL
    int2* v2c_pair = (int2*)(twt + T_TOTAL);   // NE
    int2* c2v_pair = v2c_pair + NE;            // NE
    int* ip = (int*)(c2v_pair + NE);
    int* v2c_deg    = ip; ip += NCN;    // adjacent degs -> one memset
    int* c2v_deg    = ip; ip += NVN;
    int* v2c_rowptr = ip; ip += NCN + 1;
    int* v2c_cursor = ip; ip += NCN;
    int* c2v_rowptr = ip; ip += NVN + 1;
    int* c2v_cursor = ip; ip += NVN;

    const int eb256 = (NE + 255) / 256;

    // weight transposes (independent of everything else)
    prep_kernel<<<(T_TOTAL + 255) / 256, 256, 0, stream>>>(
        v2c_w1, v2c_w2, c2v_w1, c2v_w2, pred_vals_w1, pred_cons_w1,
        pe_vals_w2, pe_cons_w2, twt);

    // CSR build
    hipMemsetAsync(v2c_deg, 0, (size_t)(NCN + NVN) * sizeof(int), stream);
    hist2_kernel<<<eb256, 256, 0, stream>>>(ei_v2c + NE, ei_c2v + NE, v2c_deg, c2v_deg);
    scan2_kernel<<<2, 1024, 0, stream>>>(v2c_deg, v2c_rowptr, v2c_cursor,
                                         c2v_deg, c2v_rowptr, c2v_cursor);
    scatter2_kernel<<<eb256, 256, 0, stream>>>(ei_v2c, ew_v2c, v2c_cursor, v2c_pair,
                                               ei_c2v, ew_c2v, c2v_cursor, c2v_pair);

    // Encoders
    encode2_kernel<<<(NVN + 3) / 4 + (NCN + 3) / 4, 256, 0, stream>>>(
        x_vals, pe_vals, enc_vals_w, enc_vals_b,
        pe_vals_w1, pe_vals_b1, twt + T_PEV_W2, pe_vals_b2,
        x_cons, pe_cons, enc_cons_w, enc_cons_b,
        pe_cons_w1, pe_cons_b1, twt + T_PEC_W2, pe_cons_b2,
        feat_v, feat_c);

    for (int i = 0; i < NLAYER; ++i) {
        // v2c: src = vals, dst = cons (in place), pred head = cons
        conv_kernel<<<(NCN + 3) / 4, 256, 0, stream>>>(
            feat_v, feat_c, v2c_rowptr, v2c_pair,
            v2c_edge_w + (size_t)i * HID, v2c_edge_b + (size_t)i * HID,
            twt + T_V2C_W1 + (size_t)i * 8192, v2c_b1 + (size_t)i * 128,
            twt + T_V2C_W2 + (size_t)i * 8192, v2c_b2 + (size_t)i * 64,
            twt + T_PC_W1, pred_cons_b1, pred_cons_w2, pred_cons_b2,
            out_c, NCN, i);
        // c2v: src = cons (updated), dst = vals (in place), pred head = vals
        conv_kernel<<<(NVN + 3) / 4, 256, 0, stream>>>(
            feat_c, feat_v, c2v_rowptr, c2v_pair,
            c2v_edge_w + (size_t)i * HID, c2v_edge_b + (size_t)i * HID,
            twt + T_C2V_W1 + (size_t)i * 8192, c2v_b1 + (size_t)i * 128,
            twt + T_C2V_W2 + (size_t)i * 8192, c2v_b2 + (size_t)i * 64,
            twt + T_PV_W1, pred_vals_b1, pred_vals_w2, pred_vals_b2,
            out, NVN, i);
    }
}

// Round 4
// 718.968 us; speedup vs baseline: 2.1824x; 2.1824x over previous
//
#include <hip/hip_runtime.h>

#define NVN 20000
#define NCN 20000
#define NE  500000
#define HID 64
#define NLAYER 3

__device__ __forceinline__ float relu_(float x) { return fmaxf(x, 0.0f); }

// ---------------- CSR build ----------------
__global__ __launch_bounds__(256) void hist2_kernel(
    const int* __restrict__ dstA, const int* __restrict__ dstB,
    int* __restrict__ degA, int* __restrict__ degB)
{
    int e = blockIdx.x * 256 + threadIdx.x;
    if (e < NE) {
        atomicAdd(&degA[dstA[e]], 1);
        atomicAdd(&degB[dstB[e]], 1);
    }
}

// 2 blocks of 1024 threads; block 0 -> A, block 1 -> B (NVN == NCN)
__global__ __launch_bounds__(1024) void scan2_kernel(
    const int* __restrict__ degA, int* __restrict__ rowptrA, int* __restrict__ cursorA,
    const int* __restrict__ degB, int* __restrict__ rowptrB, int* __restrict__ cursorB)
{
    const int n = NCN;
    const int* deg = blockIdx.x ? degB : degA;
    int* rowptr    = blockIdx.x ? rowptrB : rowptrA;
    int* cursor    = blockIdx.x ? cursorB : cursorA;
    __shared__ int part[1024];
    int t = threadIdx.x;
    int chunk = (n + 1023) / 1024;
    int base = t * chunk;
    int sum = 0;
    for (int i = 0; i < chunk; ++i) {
        int idx = base + i;
        if (idx < n) sum += deg[idx];
    }
    part[t] = sum;
    __syncthreads();
    for (int off = 1; off < 1024; off <<= 1) {
        int v = (t >= off) ? part[t - off] : 0;
        __syncthreads();
        part[t] += v;
        __syncthreads();
    }
    int run = (t == 0) ? 0 : part[t - 1];
    for (int i = 0; i < chunk; ++i) {
        int idx = base + i;
        if (idx < n) {
            int d = deg[idx];
            rowptr[idx] = run;
            cursor[idx] = run;
            run += d;
        }
    }
    if (t == 1023) rowptr[n] = part[1023];
}

__global__ __launch_bounds__(256) void scatter2_kernel(
    const int* __restrict__ eiA, const float* __restrict__ ewA,
    int* __restrict__ curA, int2* __restrict__ pairA,
    const int* __restrict__ eiB, const float* __restrict__ ewB,
    int* __restrict__ curB, int2* __restrict__ pairB)
{
    int e = blockIdx.x * 256 + threadIdx.x;
    if (e >= NE) return;
    {
        int d = eiA[NE + e];
        int pos = atomicAdd(&curA[d], 1);
        pairA[pos] = make_int2(eiA[e], __float_as_int(ewA[e]));
    }
    {
        int d = eiB[NE + e];
        int pos = atomicAdd(&curB[d], 1);
        pairB[pos] = make_int2(eiB[e], __float_as_int(ewB[e]));
    }
}

// ---------------- Encoders (both node sets in one dispatch) ----------------
__global__ __launch_bounds__(256) void encode2_kernel(
    const float* __restrict__ xv, const float* __restrict__ pev,
    const float* __restrict__ ewv, const float* __restrict__ ebv,
    const float* __restrict__ pw1v, const float* __restrict__ pb1v,
    const float* __restrict__ pw2v, const float* __restrict__ pb2v,
    const float* __restrict__ xc, const float* __restrict__ pec,
    const float* __restrict__ ewc, const float* __restrict__ ebc,
    const float* __restrict__ pw1c, const float* __restrict__ pb1c,
    const float* __restrict__ pw2c, const float* __restrict__ pb2c,
    float* __restrict__ outv, float* __restrict__ outc)
{
    __shared__ float sh[4][64];
    const int VB = (NVN + 3) / 4;
    int wave = threadIdx.x >> 6, lane = threadIdx.x & 63;
    int b = blockIdx.x;
    bool isC = (b >= VB);
    const float* x   = isC ? xc : xv;
    const float* pe  = isC ? pec : pev;
    const float* ew  = isC ? ewc : ewv;
    const float* eb  = isC ? ebc : ebv;
    const float* pw1 = isC ? pw1c : pw1v;
    const float* pb1 = isC ? pb1c : pb1v;
    const float* pw2 = isC ? pw2c : pw2v;  // original [64,32] layout
    const float* pb2 = isC ? pb2c : pb2v;
    float* out = isC ? outc : outv;
    int N = isC ? NCN : NVN;
    int n = (isC ? b - VB : b) * 4 + wave;
    if (n >= N) return;

    float accp = pb1[lane], accm = accp;
#pragma unroll
    for (int k = 0; k < 8; ++k) {
        float p = pe[n * 8 + k];
        float w = pw1[k * 64 + lane];
        accp += p * w;
        accm -= p * w;
    }
    float hs = 0.5f * (relu_(accp) + relu_(accm));
    float* my = sh[wave];
    my[lane] = hs;
    __builtin_amdgcn_wave_barrier();

    int col = lane & 31;
    float peo = pb2[col];
#pragma unroll
    for (int k = 0; k < 64; k += 4) {
        float4 hv = *(const float4*)(my + k);  // broadcast
        peo = fmaf(hv.x, pw2[(k + 0) * 32 + col], peo);  // coalesced
        peo = fmaf(hv.y, pw2[(k + 1) * 32 + col], peo);
        peo = fmaf(hv.z, pw2[(k + 2) * 32 + col], peo);
        peo = fmaf(hv.w, pw2[(k + 3) * 32 + col], peo);
    }
    float lino = x[n * 2 + 0] * ew[col] + x[n * 2 + 1] * ew[32 + col] + eb[col];
    float h = (lane < 32) ? lino : peo;
    out[n * 64 + lane] = relu_(h);
}

// ---------------- Fused GENConv + node MLP + pred head ----------------
// wave per dst node; lane = feature channel; xdst updated IN PLACE.
// Activations broadcast from LDS (float4, same-address = free); weights in
// ORIGINAL layout, coalesced across lanes (R3's per-lane weight rows were the
// 2x regression: 64 cache lines per load inst).
__global__ __launch_bounds__(256) void conv_kernel(
    const float* __restrict__ xsrc,   // [Nsrc,64]
    float* __restrict__ xdst,         // [Ndst,64] in place
    const int* __restrict__ rowptr,   // [Ndst+1]
    const int2* __restrict__ pair,    // [E] (src, bitcast(w)), dst-sorted
    const float* __restrict__ lew,    // [64]
    const float* __restrict__ leb,    // [64]
    const float* __restrict__ w1,     // [64,128] original
    const float* __restrict__ b1,     // [128]
    const float* __restrict__ w2,     // [128,64] original
    const float* __restrict__ b2,     // [64]
    const float* __restrict__ pw1,    // [64,64] original
    const float* __restrict__ pb1,    // [64]
    const float* __restrict__ pw2,    // [64]
    const float* __restrict__ pb2,    // [1]
    float* __restrict__ outp,         // write outp[n*NLAYER+layer]
    int N, int layer)
{
    __shared__ float sh[4][128];
    int wave = threadIdx.x >> 6, lane = threadIdx.x & 63;
    int n = blockIdx.x * 4 + wave;
    if (n >= N) return;

    int start = rowptr[n], end = rowptr[n + 1];
    float lw = lew[lane], lb = leb[lane];

    // chunked online softmax, 8 edges/chunk; clamp-free hot path + serial tail
    float m = -1e30f, den = 0.0f, num = 0.0f;
    int j = start;
    for (; j + 8 <= end; j += 8) {
        int idx[8]; float wv[8], msg[8];
#pragma unroll
        for (int c = 0; c < 8; ++c) {
            int2 p = pair[j + c];
            idx[c] = p.x;
            wv[c] = __int_as_float(p.y);
        }
#pragma unroll
        for (int c = 0; c < 8; ++c) {
            float xv = xsrc[idx[c] * 64 + lane];
            msg[c] = relu_(fmaf(wv[c], lw, xv + lb)) + 1e-7f;
        }
        float a0 = fmaxf(msg[0], msg[1]), a1 = fmaxf(msg[2], msg[3]);
        float a2 = fmaxf(msg[4], msg[5]), a3 = fmaxf(msg[6], msg[7]);
        float mnew = fmaxf(m, fmaxf(fmaxf(a0, a1), fmaxf(a2, a3)));
        float sc = __expf(m - mnew);  // 0 on first chunk
        float cden = 0.0f, cnum = 0.0f;
#pragma unroll
        for (int c = 0; c < 8; ++c) {
            float e = __expf(msg[c] - mnew);
            cden += e;
            cnum = fmaf(e, msg[c], cnum);
        }
        den = fmaf(den, sc, cden);
        num = fmaf(num, sc, cnum);
        m = mnew;
    }
    for (; j < end; ++j) {  // tail < 8 edges
        int2 p = pair[j];
        float xv = xsrc[p.x * 64 + lane];
        float msg = relu_(fmaf(__int_as_float(p.y), lw, xv + lb)) + 1e-7f;
        float mnew = fmaxf(m, msg);
        float sc = __expf(m - mnew);
        float e = __expf(msg - mnew);
        den = fmaf(den, sc, e);
        num = fmaf(num, sc, e * msg);
        m = mnew;
    }
    float o = num / (den + 1e-16f) + xdst[n * 64 + lane];

    float* my = sh[wave];
    my[lane] = o;
    __builtin_amdgcn_wave_barrier();

    // 64 -> 128: lane owns outputs lane, lane+64; weights coalesced
    float h0 = b1[lane], h1 = b1[64 + lane];
#pragma unroll
    for (int k = 0; k < 64; k += 4) {
        float4 ov = *(const float4*)(my + k);
        h0 = fmaf(ov.x, w1[(k + 0) * 128 + lane], h0);
        h1 = fmaf(ov.x, w1[(k + 0) * 128 + 64 + lane], h1);
        h0 = fmaf(ov.y, w1[(k + 1) * 128 + lane], h0);
        h1 = fmaf(ov.y, w1[(k + 1) * 128 + 64 + lane], h1);
        h0 = fmaf(ov.z, w1[(k + 2) * 128 + lane], h0);
        h1 = fmaf(ov.z, w1[(k + 2) * 128 + 64 + lane], h1);
        h0 = fmaf(ov.w, w1[(k + 3) * 128 + lane], h0);
        h1 = fmaf(ov.w, w1[(k + 3) * 128 + 64 + lane], h1);
    }
    h0 = relu_(h0);
    h1 = relu_(h1);
    __builtin_amdgcn_wave_barrier();
    my[lane] = h0;
    my[64 + lane] = h1;
    __builtin_amdgcn_wave_barrier();

    // 128 -> 64: lane owns output lane
    float r = b2[lane];
#pragma unroll
    for (int k = 0; k < 128; k += 4) {
        float4 hv = *(const float4*)(my + k);
        r = fmaf(hv.x, w2[(k + 0) * 64 + lane], r);
        r = fmaf(hv.y, w2[(k + 1) * 64 + lane], r);
        r = fmaf(hv.z, w2[(k + 2) * 64 + lane], r);
        r = fmaf(hv.w, w2[(k + 3) * 64 + lane], r);
    }
    xdst[n * 64 + lane] = r;
    __builtin_amdgcn_wave_barrier();

    // pred head: relu(r@pw1+pb1)@pw2 + pb2
    my[lane] = r;
    __builtin_amdgcn_wave_barrier();
    float ph = pb1[lane];
#pragma unroll
    for (int k = 0; k < 64; k += 4) {
        float4 rv = *(const float4*)(my + k);
        ph = fmaf(rv.x, pw1[(k + 0) * 64 + lane], ph);
        ph = fmaf(rv.y, pw1[(k + 1) * 64 + lane], ph);
        ph = fmaf(rv.z, pw1[(k + 2) * 64 + lane], ph);
        ph = fmaf(rv.w, pw1[(k + 3) * 64 + lane], ph);
    }
    ph = relu_(ph);
    float partial = ph * pw2[lane];
#pragma unroll
    for (int off = 32; off > 0; off >>= 1)
        partial += __shfl_down(partial, off, 64);
    if (lane == 0) outp[n * NLAYER + layer] = partial + pb2[0];
}

extern "C" void kernel_launch(void* const* d_in, const int* in_sizes, int n_in,
                              void* d_out, int out_size, void* d_ws, size_t ws_size,
                              hipStream_t stream)
{
    const float* x_vals   = (const float*)d_in[0];
    const float* x_cons   = (const float*)d_in[1];
    const float* pe_vals  = (const float*)d_in[2];
    const float* pe_cons  = (const float*)d_in[3];
    const int*   ei_v2c   = (const int*)d_in[4];   // [2,E]
    const int*   ei_c2v   = (const int*)d_in[5];   // [2,E]
    const float* ew_v2c   = (const float*)d_in[6]; // [E,1]
    const float* ew_c2v   = (const float*)d_in[7];
    const float* enc_vals_w = (const float*)d_in[8];
    const float* enc_vals_b = (const float*)d_in[9];
    const float* pe_vals_w1 = (const float*)d_in[10];
    const float* pe_vals_b1 = (const float*)d_in[11];
    const float* pe_vals_w2 = (const float*)d_in[12];
    const float* pe_vals_b2 = (const float*)d_in[13];
    const float* enc_cons_w = (const float*)d_in[14];
    const float* enc_cons_b = (const float*)d_in[15];
    const float* pe_cons_w1 = (const float*)d_in[16];
    const float* pe_cons_b1 = (const float*)d_in[17];
    const float* pe_cons_w2 = (const float*)d_in[18];
    const float* pe_cons_b2 = (const float*)d_in[19];
    const float* v2c_edge_w = (const float*)d_in[20]; // [NL,1,64]
    const float* v2c_edge_b = (const float*)d_in[21]; // [NL,64]
    const float* v2c_w1     = (const float*)d_in[22]; // [NL,64,128]
    const float* v2c_b1     = (const float*)d_in[23]; // [NL,128]
    const float* v2c_w2     = (const float*)d_in[24]; // [NL,128,64]
    const float* v2c_b2     = (const float*)d_in[25]; // [NL,64]
    const float* c2v_edge_w = (const float*)d_in[26];
    const float* c2v_edge_b = (const float*)d_in[27];
    const float* c2v_w1     = (const float*)d_in[28];
    const float* c2v_b1     = (const float*)d_in[29];
    const float* c2v_w2     = (const float*)d_in[30];
    const float* c2v_b2     = (const float*)d_in[31];
    const float* pred_vals_w1 = (const float*)d_in[32];
    const float* pred_vals_b1 = (const float*)d_in[33];
    const float* pred_vals_w2 = (const float*)d_in[34];
    const float* pred_vals_b2 = (const float*)d_in[35];
    const float* pred_cons_w1 = (const float*)d_in[36];
    const float* pred_cons_b1 = (const float*)d_in[37];
    const float* pred_cons_w2 = (const float*)d_in[38];
    const float* pred_cons_b2 = (const float*)d_in[39];

    float* out = (float*)d_out;
    float* out_c = out + (size_t)NVN * NLAYER;

    const size_t NF = (size_t)NVN * 64;

    // Workspace layout
    float* ws     = (float*)d_ws;
    float* feat_v = ws;                 // NF (in-place across layers)
    float* feat_c = feat_v + NF;        // NF
    int2* v2c_pair = (int2*)(feat_c + NF);     // NE
    int2* c2v_pair = v2c_pair + NE;            // NE
    int* ip = (int*)(c2v_pair + NE);
    int* v2c_deg    = ip; ip += NCN;    // adjacent degs -> one memset
    int* c2v_deg    = ip; ip += NVN;
    int* v2c_rowptr = ip; ip += NCN + 1;
    int* v2c_cursor = ip; ip += NCN;
    int* c2v_rowptr = ip; ip += NVN + 1;
    int* c2v_cursor = ip; ip += NVN;

    const int eb256 = (NE + 255) / 256;

    // CSR build (edge structure is layer-invariant)
    hipMemsetAsync(v2c_deg, 0, (size_t)(NCN + NVN) * sizeof(int), stream);
    hist2_kernel<<<eb256, 256, 0, stream>>>(ei_v2c + NE, ei_c2v + NE, v2c_deg, c2v_deg);
    scan2_kernel<<<2, 1024, 0, stream>>>(v2c_deg, v2c_rowptr, v2c_cursor,
                                         c2v_deg, c2v_rowptr, c2v_cursor);
    scatter2_kernel<<<eb256, 256, 0, stream>>>(ei_v2c, ew_v2c, v2c_cursor, v2c_pair,
                                               ei_c2v, ew_c2v, c2v_cursor, c2v_pair);

    // Encoders
    encode2_kernel<<<(NVN + 3) / 4 + (NCN + 3) / 4, 256, 0, stream>>>(
        x_vals, pe_vals, enc_vals_w, enc_vals_b,
        pe_vals_w1, pe_vals_b1, pe_vals_w2, pe_vals_b2,
        x_cons, pe_cons, enc_cons_w, enc_cons_b,
        pe_cons_w1, pe_cons_b1, pe_cons_w2, pe_cons_b2,
        feat_v, feat_c);

    for (int i = 0; i < NLAYER; ++i) {
        // v2c: src = vals, dst = cons (in place), pred head = cons
        conv_kernel<<<(NCN + 3) / 4, 256, 0, stream>>>(
            feat_v, feat_c, v2c_rowptr, v2c_pair,
            v2c_edge_w + (size_t)i * HID, v2c_edge_b + (size_t)i * HID,
            v2c_w1 + (size_t)i * 8192, v2c_b1 + (size_t)i * 128,
            v2c_w2 + (size_t)i * 8192, v2c_b2 + (size_t)i * 64,
            pred_cons_w1, pred_cons_b1, pred_cons_w2, pred_cons_b2,
            out_c, NCN, i);
        // c2v: src = cons (updated), dst = vals (in place), pred head = vals
        conv_kernel<<<(NVN + 3) / 4, 256, 0, stream>>>(
            feat_c, feat_v, c2v_rowptr, c2v_pair,
            c2v_edge_w + (size_t)i * HID, c2v_edge_b + (size_t)i * HID,
            c2v_w1 + (size_t)i * 8192, c2v_b1 + (size_t)i * 128,
            c2v_w2 + (size_t)i * 8192, c2v_b2 + (size_t)i * 64,
            pred_vals_w1, pred_vals_b1, pred_vals_w2, pred_vals_b2,
            out, NVN, i);
    }
}

// Round 5
// 625.177 us; speedup vs baseline: 2.5099x; 1.1500x over previous
//
#include <hip/hip_runtime.h>

#define NVN 20000
#define NCN 20000
#define NE  500000
#define HID 64
#define NLAYER 3
#define TN 40   // nodes per MLP tile; 20000/40 = 500 tiles, grid 250 -> 2 tiles/block

__device__ __forceinline__ float relu_(float x) { return fmaxf(x, 0.0f); }

// ---------------- CSR build ----------------
__global__ __launch_bounds__(256) void hist2_kernel(
    const int* __restrict__ dstA, const int* __restrict__ dstB,
    int* __restrict__ degA, int* __restrict__ degB)
{
    int e = blockIdx.x * 256 + threadIdx.x;
    if (e < NE) {
        atomicAdd(&degA[dstA[e]], 1);
        atomicAdd(&degB[dstB[e]], 1);
    }
}

// 2 blocks of 1024 threads; block 0 -> A, block 1 -> B (NVN == NCN)
__global__ __launch_bounds__(1024) void scan2_kernel(
    const int* __restrict__ degA, int* __restrict__ rowptrA, int* __restrict__ cursorA,
    const int* __restrict__ degB, int* __restrict__ rowptrB, int* __restrict__ cursorB)
{
    const int n = NCN;
    const int* deg = blockIdx.x ? degB : degA;
    int* rowptr    = blockIdx.x ? rowptrB : rowptrA;
    int* cursor    = blockIdx.x ? cursorB : cursorA;
    __shared__ int part[1024];
    int t = threadIdx.x;
    int chunk = (n + 1023) / 1024;
    int base = t * chunk;
    int sum = 0;
    for (int i = 0; i < chunk; ++i) {
        int idx = base + i;
        if (idx < n) sum += deg[idx];
    }
    part[t] = sum;
    __syncthreads();
    for (int off = 1; off < 1024; off <<= 1) {
        int v = (t >= off) ? part[t - off] : 0;
        __syncthreads();
        part[t] += v;
        __syncthreads();
    }
    int run = (t == 0) ? 0 : part[t - 1];
    for (int i = 0; i < chunk; ++i) {
        int idx = base + i;
        if (idx < n) {
            int d = deg[idx];
            rowptr[idx] = run;
            cursor[idx] = run;
            run += d;
        }
    }
    if (t == 1023) rowptr[n] = part[1023];
}

__global__ __launch_bounds__(256) void scatter2_kernel(
    const int* __restrict__ eiA, const float* __restrict__ ewA,
    int* __restrict__ curA, int2* __restrict__ pairA,
    const int* __restrict__ eiB, const float* __restrict__ ewB,
    int* __restrict__ curB, int2* __restrict__ pairB)
{
    int e = blockIdx.x * 256 + threadIdx.x;
    if (e >= NE) return;
    {
        int d = eiA[NE + e];
        int pos = atomicAdd(&curA[d], 1);
        pairA[pos] = make_int2(eiA[e], __float_as_int(ewA[e]));
    }
    {
        int d = eiB[NE + e];
        int pos = atomicAdd(&curB[d], 1);
        pairB[pos] = make_int2(eiB[e], __float_as_int(ewB[e]));
    }
}

// ---------------- Encoders (both node sets in one dispatch) ----------------
__global__ __launch_bounds__(256) void encode2_kernel(
    const float* __restrict__ xv, const float* __restrict__ pev,
    const float* __restrict__ ewv, const float* __restrict__ ebv,
    const float* __restrict__ pw1v, const float* __restrict__ pb1v,
    const float* __restrict__ pw2v, const float* __restrict__ pb2v,
    const float* __restrict__ xc, const float* __restrict__ pec,
    const float* __restrict__ ewc, const float* __restrict__ ebc,
    const float* __restrict__ pw1c, const float* __restrict__ pb1c,
    const float* __restrict__ pw2c, const float* __restrict__ pb2c,
    float* __restrict__ outv, float* __restrict__ outc)
{
    __shared__ float sh[4][64];
    const int VB = (NVN + 3) / 4;
    int wave = threadIdx.x >> 6, lane = threadIdx.x & 63;
    int b = blockIdx.x;
    bool isC = (b >= VB);
    const float* x   = isC ? xc : xv;
    const float* pe  = isC ? pec : pev;
    const float* ew  = isC ? ewc : ewv;
    const float* eb  = isC ? ebc : ebv;
    const float* pw1 = isC ? pw1c : pw1v;
    const float* pb1 = isC ? pb1c : pb1v;
    const float* pw2 = isC ? pw2c : pw2v;
    const float* pb2 = isC ? pb2c : pb2v;
    float* out = isC ? outc : outv;
    int N = isC ? NCN : NVN;
    int n = (isC ? b - VB : b) * 4 + wave;
    if (n >= N) return;

    float accp = pb1[lane], accm = accp;
#pragma unroll
    for (int k = 0; k < 8; ++k) {
        float p = pe[n * 8 + k];
        float w = pw1[k * 64 + lane];
        accp += p * w;
        accm -= p * w;
    }
    float hs = 0.5f * (relu_(accp) + relu_(accm));
    float* my = sh[wave];
    my[lane] = hs;
    __builtin_amdgcn_wave_barrier();

    int col = lane & 31;
    float peo = pb2[col];
#pragma unroll
    for (int k = 0; k < 64; k += 4) {
        float4 hv = *(const float4*)(my + k);
        peo = fmaf(hv.x, pw2[(k + 0) * 32 + col], peo);
        peo = fmaf(hv.y, pw2[(k + 1) * 32 + col], peo);
        peo = fmaf(hv.z, pw2[(k + 2) * 32 + col], peo);
        peo = fmaf(hv.w, pw2[(k + 3) * 32 + col], peo);
    }
    float lino = x[n * 2 + 0] * ew[col] + x[n * 2 + 1] * ew[32 + col] + eb[col];
    float h = (lane < 32) ? lino : peo;
    out[n * 64 + lane] = relu_(h);
}

// ---------------- Edge aggregation: online softmax, wave per dst node ------
__global__ __launch_bounds__(256) void edge_agg_kernel(
    const float* __restrict__ xsrc,   // [Nsrc,64]
    const float* __restrict__ xdst,   // [Ndst,64]
    const int* __restrict__ rowptr,   // [Ndst+1]
    const int2* __restrict__ pair,    // [E] (src, bitcast(w)), dst-sorted
    const float* __restrict__ lew,    // [64]
    const float* __restrict__ leb,    // [64]
    float* __restrict__ oa,           // [Ndst,64]  agg + xdst
    int N)
{
    int wave = threadIdx.x >> 6, lane = threadIdx.x & 63;
    int n = blockIdx.x * 4 + wave;
    if (n >= N) return;

    int start = rowptr[n], end = rowptr[n + 1];
    float lw = lew[lane], lb = leb[lane];

    float m = -1e30f, den = 0.0f, num = 0.0f;
    int j = start;
    for (; j + 8 <= end; j += 8) {
        int idx[8]; float wv[8], msg[8];
#pragma unroll
        for (int c = 0; c < 8; ++c) {
            int2 p = pair[j + c];
            idx[c] = p.x;
            wv[c] = __int_as_float(p.y);
        }
#pragma unroll
        for (int c = 0; c < 8; ++c) {
            float xv = xsrc[idx[c] * 64 + lane];
            msg[c] = relu_(fmaf(wv[c], lw, xv + lb)) + 1e-7f;
        }
        float a0 = fmaxf(msg[0], msg[1]), a1 = fmaxf(msg[2], msg[3]);
        float a2 = fmaxf(msg[4], msg[5]), a3 = fmaxf(msg[6], msg[7]);
        float mnew = fmaxf(m, fmaxf(fmaxf(a0, a1), fmaxf(a2, a3)));
        float sc = __expf(m - mnew);
        float cden = 0.0f, cnum = 0.0f;
#pragma unroll
        for (int c = 0; c < 8; ++c) {
            float e = __expf(msg[c] - mnew);
            cden += e;
            cnum = fmaf(e, msg[c], cnum);
        }
        den = fmaf(den, sc, cden);
        num = fmaf(num, sc, cnum);
        m = mnew;
    }
    for (; j < end; ++j) {
        int2 p = pair[j];
        float xv = xsrc[p.x * 64 + lane];
        float msg = relu_(fmaf(__int_as_float(p.y), lw, xv + lb)) + 1e-7f;
        float mnew = fmaxf(m, msg);
        float sc = __expf(m - mnew);
        float e = __expf(msg - mnew);
        den = fmaf(den, sc, e);
        num = fmaf(num, sc, e * msg);
        m = mnew;
    }
    oa[n * 64 + lane] = num / (den + 1e-16f) + xdst[n * 64 + lane];
}

// ---------------- Persistent-weights MLP + pred head ----------------------
// r = relu(oa@w1+b1)@w2+b2  -> feat (in place target)
// pred = relu(r@pw1+pb1)@pw2+pb2 -> outp[n*NLAYER+layer]
// grid 250 blocks (1/CU), each block: weights in LDS once, 2 tiles of 40 nodes.
__global__ __launch_bounds__(256) void mlp_kernel(
    const float* __restrict__ oa,    // [N,64]
    float* __restrict__ feat,        // [N,64]
    const float* __restrict__ w1,    // [64,128]
    const float* __restrict__ b1,    // [128]
    const float* __restrict__ w2,    // [128,64]
    const float* __restrict__ b2,    // [64]
    const float* __restrict__ pw1,   // [64,64]
    const float* __restrict__ pb1,   // [64]
    const float* __restrict__ pw2,   // [64]
    const float* __restrict__ pb2,   // [1]
    float* __restrict__ outp,
    int N, int layer)
{
    __shared__ float w1s[64 * 128];
    __shared__ float w2s[128 * 64];
    __shared__ float pw1s[64 * 64];
    __shared__ float b1s[128];
    __shared__ float b2s[64];
    __shared__ float pb1s[64];
    __shared__ float pw2s[64];
    __shared__ float act[TN][68];    // row pad 68 (16B-aligned rows)
    __shared__ float hid[TN][132];   // row pad 132

    int tid = threadIdx.x;
    for (int i = tid; i < 64 * 128; i += 256) w1s[i] = w1[i];
    for (int i = tid; i < 128 * 64; i += 256) w2s[i] = w2[i];
    for (int i = tid; i < 64 * 64; i += 256) pw1s[i] = pw1[i];
    if (tid < 128) b1s[tid] = b1[tid];
    if (tid < 64) { b2s[tid] = b2[tid]; pb1s[tid] = pb1[tid]; pw2s[tid] = pw2[tid]; }
    float pb2v = pb2[0];

    int o4 = (tid & 31) * 4;        // L1 col base (0..124)
    int o2 = (tid & 31) * 2;        // L2/pred col base (0..62)
    int n5 = (tid >> 5) * 5;        // row base in tile (0..35)
    __syncthreads();

    int ntiles = N / TN;            // exact: 20000/40 = 500
    for (int tile = blockIdx.x; tile < ntiles; tile += gridDim.x) {
        int base = tile * TN;
        // stage act
        {
            const float* g = oa + (size_t)base * 64;
            for (int i = tid; i < TN * 64; i += 256)
                act[i >> 6][i & 63] = g[i];
        }
        __syncthreads();

        // L1: hid = relu(act @ w1 + b1); thread tile 5n x 4o
        {
            float acc[5][4];
#pragma unroll
            for (int i = 0; i < 5; ++i)
#pragma unroll
                for (int q = 0; q < 4; ++q) acc[i][q] = b1s[o4 + q];
            for (int k = 0; k < 64; k += 4) {
                float4 a[5];
#pragma unroll
                for (int i = 0; i < 5; ++i) a[i] = *(const float4*)&act[n5 + i][k];
                float4 w0 = *(const float4*)&w1s[(k + 0) * 128 + o4];
                float4 wq1 = *(const float4*)&w1s[(k + 1) * 128 + o4];
                float4 wq2 = *(const float4*)&w1s[(k + 2) * 128 + o4];
                float4 wq3 = *(const float4*)&w1s[(k + 3) * 128 + o4];
#pragma unroll
                for (int i = 0; i < 5; ++i) {
                    acc[i][0] = fmaf(a[i].x, w0.x, acc[i][0]);
                    acc[i][1] = fmaf(a[i].x, w0.y, acc[i][1]);
                    acc[i][2] = fmaf(a[i].x, w0.z, acc[i][2]);
                    acc[i][3] = fmaf(a[i].x, w0.w, acc[i][3]);
                    acc[i][0] = fmaf(a[i].y, wq1.x, acc[i][0]);
                    acc[i][1] = fmaf(a[i].y, wq1.y, acc[i][1]);
                    acc[i][2] = fmaf(a[i].y, wq1.z, acc[i][2]);
                    acc[i][3] = fmaf(a[i].y, wq1.w, acc[i][3]);
                    acc[i][0] = fmaf(a[i].z, wq2.x, acc[i][0]);
                    acc[i][1] = fmaf(a[i].z, wq2.y, acc[i][1]);
                    acc[i][2] = fmaf(a[i].z, wq2.z, acc[i][2]);
                    acc[i][3] = fmaf(a[i].z, wq2.w, acc[i][3]);
                    acc[i][0] = fmaf(a[i].w, wq3.x, acc[i][0]);
                    acc[i][1] = fmaf(a[i].w, wq3.y, acc[i][1]);
                    acc[i][2] = fmaf(a[i].w, wq3.z, acc[i][2]);
                    acc[i][3] = fmaf(a[i].w, wq3.w, acc[i][3]);
                }
            }
#pragma unroll
            for (int i = 0; i < 5; ++i) {
                float4 h4 = make_float4(relu_(acc[i][0]), relu_(acc[i][1]),
                                        relu_(acc[i][2]), relu_(acc[i][3]));
                *(float4*)&hid[n5 + i][o4] = h4;
            }
        }
        __syncthreads();

        // L2: r = hid @ w2 + b2; thread tile 5n x 2o; write feat + act (reuse)
        {
            float acc[5][2];
#pragma unroll
            for (int i = 0; i < 5; ++i) { acc[i][0] = b2s[o2]; acc[i][1] = b2s[o2 + 1]; }
            for (int k = 0; k < 128; k += 4) {
                float4 a[5];
#pragma unroll
                for (int i = 0; i < 5; ++i) a[i] = *(const float4*)&hid[n5 + i][k];
                float2 w0 = *(const float2*)&w2s[(k + 0) * 64 + o2];
                float2 wq1 = *(const float2*)&w2s[(k + 1) * 64 + o2];
                float2 wq2 = *(const float2*)&w2s[(k + 2) * 64 + o2];
                float2 wq3 = *(const float2*)&w2s[(k + 3) * 64 + o2];
#pragma unroll
                for (int i = 0; i < 5; ++i) {
                    acc[i][0] = fmaf(a[i].x, w0.x, acc[i][0]);
                    acc[i][1] = fmaf(a[i].x, w0.y, acc[i][1]);
                    acc[i][0] = fmaf(a[i].y, wq1.x, acc[i][0]);
                    acc[i][1] = fmaf(a[i].y, wq1.y, acc[i][1]);
                    acc[i][0] = fmaf(a[i].z, wq2.x, acc[i][0]);
                    acc[i][1] = fmaf(a[i].z, wq2.y, acc[i][1]);
                    acc[i][0] = fmaf(a[i].w, wq3.x, acc[i][0]);
                    acc[i][1] = fmaf(a[i].w, wq3.y, acc[i][1]);
                }
            }
#pragma unroll
            for (int i = 0; i < 5; ++i) {
                float2 r2 = make_float2(acc[i][0], acc[i][1]);
                *(float2*)&feat[(size_t)(base + n5 + i) * 64 + o2] = r2;
                *(float2*)&act[n5 + i][o2] = r2;   // pred input
            }
        }
        __syncthreads();

        // Pred: ph = relu(act @ pw1 + pb1); contrib = ph*pw2; reduce over cols
        {
            float acc[5][2];
#pragma unroll
            for (int i = 0; i < 5; ++i) { acc[i][0] = pb1s[o2]; acc[i][1] = pb1s[o2 + 1]; }
            for (int k = 0; k < 64; k += 4) {
                float4 a[5];
#pragma unroll
                for (int i = 0; i < 5; ++i) a[i] = *(const float4*)&act[n5 + i][k];
                float2 w0 = *(const float2*)&pw1s[(k + 0) * 64 + o2];
                float2 wq1 = *(const float2*)&pw1s[(k + 1) * 64 + o2];
                float2 wq2 = *(const float2*)&pw1s[(k + 2) * 64 + o2];
                float2 wq3 = *(const float2*)&pw1s[(k + 3) * 64 + o2];
#pragma unroll
                for (int i = 0; i < 5; ++i) {
                    acc[i][0] = fmaf(a[i].x, w0.x, acc[i][0]);
                    acc[i][1] = fmaf(a[i].x, w0.y, acc[i][1]);
                    acc[i][0] = fmaf(a[i].y, wq1.x, acc[i][0]);
                    acc[i][1] = fmaf(a[i].y, wq1.y, acc[i][1]);
                    acc[i][0] = fmaf(a[i].z, wq2.x, acc[i][0]);
                    acc[i][1] = fmaf(a[i].z, wq2.y, acc[i][1]);
                    acc[i][0] = fmaf(a[i].w, wq3.x, acc[i][0]);
                    acc[i][1] = fmaf(a[i].w, wq3.y, acc[i][1]);
                }
            }
            float pw2a = pw2s[o2], pw2b = pw2s[o2 + 1];
            float ps[5];
#pragma unroll
            for (int i = 0; i < 5; ++i)
                ps[i] = relu_(acc[i][0]) * pw2a + relu_(acc[i][1]) * pw2b;
            // reduce across the 32 col-threads (same half-wave, same n-group)
#pragma unroll
            for (int msk = 16; msk >= 1; msk >>= 1) {
#pragma unroll
                for (int i = 0; i < 5; ++i)
                    ps[i] += __shfl_xor(ps[i], msk, 64);
            }
            if ((tid & 31) == 0) {
#pragma unroll
                for (int i = 0; i < 5; ++i)
                    outp[(size_t)(base + n5 + i) * NLAYER + layer] = ps[i] + pb2v;
            }
        }
        __syncthreads();  // protect act/hid before next tile
    }
}

extern "C" void kernel_launch(void* const* d_in, const int* in_sizes, int n_in,
                              void* d_out, int out_size, void* d_ws, size_t ws_size,
                              hipStream_t stream)
{
    const float* x_vals   = (const float*)d_in[0];
    const float* x_cons   = (const float*)d_in[1];
    const float* pe_vals  = (const float*)d_in[2];
    const float* pe_cons  = (const float*)d_in[3];
    const int*   ei_v2c   = (const int*)d_in[4];   // [2,E]
    const int*   ei_c2v   = (const int*)d_in[5];   // [2,E]
    const float* ew_v2c   = (const float*)d_in[6]; // [E,1]
    const float* ew_c2v   = (const float*)d_in[7];
    const float* enc_vals_w = (const float*)d_in[8];
    const float* enc_vals_b = (const float*)d_in[9];
    const float* pe_vals_w1 = (const float*)d_in[10];
    const float* pe_vals_b1 = (const float*)d_in[11];
    const float* pe_vals_w2 = (const float*)d_in[12];
    const float* pe_vals_b2 = (const float*)d_in[13];
    const float* enc_cons_w = (const float*)d_in[14];
    const float* enc_cons_b = (const float*)d_in[15];
    const float* pe_cons_w1 = (const float*)d_in[16];
    const float* pe_cons_b1 = (const float*)d_in[17];
    const float* pe_cons_w2 = (const float*)d_in[18];
    const float* pe_cons_b2 = (const float*)d_in[19];
    const float* v2c_edge_w = (const float*)d_in[20]; // [NL,1,64]
    const float* v2c_edge_b = (const float*)d_in[21]; // [NL,64]
    const float* v2c_w1     = (const float*)d_in[22]; // [NL,64,128]
    const float* v2c_b1     = (const float*)d_in[23]; // [NL,128]
    const float* v2c_w2     = (const float*)d_in[24]; // [NL,128,64]
    const float* v2c_b2     = (const float*)d_in[25]; // [NL,64]
    const float* c2v_edge_w = (const float*)d_in[26];
    const float* c2v_edge_b = (const float*)d_in[27];
    const float* c2v_w1     = (const float*)d_in[28];
    const float* c2v_b1     = (const float*)d_in[29];
    const float* c2v_w2     = (const float*)d_in[30];
    const float* c2v_b2     = (const float*)d_in[31];
    const float* pred_vals_w1 = (const float*)d_in[32];
    const float* pred_vals_b1 = (const float*)d_in[33];
    const float* pred_vals_w2 = (const float*)d_in[34];
    const float* pred_vals_b2 = (const float*)d_in[35];
    const float* pred_cons_w1 = (const float*)d_in[36];
    const float* pred_cons_b1 = (const float*)d_in[37];
    const float* pred_cons_w2 = (const float*)d_in[38];
    const float* pred_cons_b2 = (const float*)d_in[39];

    float* out = (float*)d_out;
    float* out_c = out + (size_t)NVN * NLAYER;

    const size_t NF = (size_t)NVN * 64;

    // Workspace layout
    float* ws     = (float*)d_ws;
    float* feat_v = ws;                 // NF (in-place across layers)
    float* feat_c = feat_v + NF;        // NF
    float* oa     = feat_c + NF;        // NF (edge-agg output)
    int2* v2c_pair = (int2*)(oa + NF);         // NE
    int2* c2v_pair = v2c_pair + NE;            // NE
    int* ip = (int*)(c2v_pair + NE);
    int* v2c_deg    = ip; ip += NCN;    // adjacent degs -> one memset
    int* c2v_deg    = ip; ip += NVN;
    int* v2c_rowptr = ip; ip += NCN + 1;
    int* v2c_cursor = ip; ip += NCN;
    int* c2v_rowptr = ip; ip += NVN + 1;
    int* c2v_cursor = ip; ip += NVN;

    const int eb256 = (NE + 255) / 256;

    // CSR build (edge structure is layer-invariant)
    hipMemsetAsync(v2c_deg, 0, (size_t)(NCN + NVN) * sizeof(int), stream);
    hist2_kernel<<<eb256, 256, 0, stream>>>(ei_v2c + NE, ei_c2v + NE, v2c_deg, c2v_deg);
    scan2_kernel<<<2, 1024, 0, stream>>>(v2c_deg, v2c_rowptr, v2c_cursor,
                                         c2v_deg, c2v_rowptr, c2v_cursor);
    scatter2_kernel<<<eb256, 256, 0, stream>>>(ei_v2c, ew_v2c, v2c_cursor, v2c_pair,
                                               ei_c2v, ew_c2v, c2v_cursor, c2v_pair);

    // Encoders
    encode2_kernel<<<(NVN + 3) / 4 + (NCN + 3) / 4, 256, 0, stream>>>(
        x_vals, pe_vals, enc_vals_w, enc_vals_b,
        pe_vals_w1, pe_vals_b1, pe_vals_w2, pe_vals_b2,
        x_cons, pe_cons, enc_cons_w, enc_cons_b,
        pe_cons_w1, pe_cons_b1, pe_cons_w2, pe_cons_b2,
        feat_v, feat_c);

    for (int i = 0; i < NLAYER; ++i) {
        // v2c: src = vals, dst = cons
        edge_agg_kernel<<<(NCN + 3) / 4, 256, 0, stream>>>(
            feat_v, feat_c, v2c_rowptr, v2c_pair,
            v2c_edge_w + (size_t)i * HID, v2c_edge_b + (size_t)i * HID,
            oa, NCN);
        mlp_kernel<<<250, 256, 0, stream>>>(
            oa, feat_c,
            v2c_w1 + (size_t)i * 8192, v2c_b1 + (size_t)i * 128,
            v2c_w2 + (size_t)i * 8192, v2c_b2 + (size_t)i * 64,
            pred_cons_w1, pred_cons_b1, pred_cons_w2, pred_cons_b2,
            out_c, NCN, i);
        // c2v: src = cons (updated), dst = vals
        edge_agg_kernel<<<(NVN + 3) / 4, 256, 0, stream>>>(
            feat_c, feat_v, c2v_rowptr, c2v_pair,
            c2v_edge_w + (size_t)i * HID, c2v_edge_b + (size_t)i * HID,
            oa, NVN);
        mlp_kernel<<<250, 256, 0, stream>>>(
            oa, feat_v,
            c2v_w1 + (size_t)i * 8192, c2v_b1 + (size_t)i * 128,
            c2v_w2 + (size_t)i * 8192, c2v_b2 + (size_t)i * 64,
            pred_vals_w1, pred_vals_b1, pred_vals_w2, pred_vals_b2,
            out, NVN, i);
    }
}